// Round 6
// baseline (1520.501 us; speedup 1.0000x reference)
//
#include <hip/hip_runtime.h>
#include <stdint.h>

typedef unsigned short U16;
typedef float f32x4 __attribute__((ext_vector_type(4)));
typedef __bf16 bf16x8 __attribute__((ext_vector_type(8)));

static __device__ __forceinline__ U16 f2bf(float x) {
  union { float f; unsigned u; } v; v.f = x;
  unsigned r = v.u + 0x7FFFu + ((v.u >> 16) & 1u);
  return (U16)(r >> 16);
}
static __device__ __forceinline__ float bf2f(U16 h) {
  union { unsigned u; float f; } v; v.u = ((unsigned)h) << 16;
  return v.f;
}

static __device__ __forceinline__ void gload_lds16(const void* g, void* l) {
  __builtin_amdgcn_global_load_lds(
      (const __attribute__((address_space(1))) void*)g,
      (__attribute__((address_space(3))) void*)l, 16, 0, 0);
}

// ---------------- hidden (fp32) -> bf16 -------------------------------------
__global__ __launch_bounds__(256) void k_convert(const float* __restrict__ src,
                                                 U16* __restrict__ dst, long n) {
  long base = ((long)blockIdx.x * 256 + threadIdx.x) * 8;
  if (base >= n) return;
  const float4* s = (const float4*)(src + base);
  float4 a = s[0], b = s[1];
  U16 o[8] = { f2bf(a.x), f2bf(a.y), f2bf(a.z), f2bf(a.w),
               f2bf(b.x), f2bf(b.y), f2bf(b.z), f2bf(b.w) };
  *(uint4*)(dst + base) = *(const uint4*)o;
}

// ---------------- W[K][N] (fp32) -> Wt[N][K] bf16 ----------------------------
__global__ __launch_bounds__(256) void k_transpose(const float* __restrict__ src,
                                                   U16* __restrict__ dst,
                                                   int K, int N) {
  __shared__ U16 tile[32][33];
  int n0 = blockIdx.x * 32, k0 = blockIdx.y * 32;
  int tx = threadIdx.x & 31, ty = threadIdx.x >> 5;
#pragma unroll
  for (int r = 0; r < 4; ++r) {
    int k = k0 + ty + r * 8;
    tile[ty + r * 8][tx] = f2bf(src[(long)k * N + n0 + tx]);
  }
  __syncthreads();
#pragma unroll
  for (int r = 0; r < 4; ++r) {
    int n = n0 + ty + r * 8;
    dst[(long)n * K + k0 + tx] = tile[tx][ty + r * 8];
  }
}

// ---------------- V section of QKV -> VT[b*8+kvh][d][s] bf16 -----------------
__global__ __launch_bounds__(256) void k_vtrans(const U16* __restrict__ QKV,
                                                U16* __restrict__ VT) {
  __shared__ U16 tile[32][33];
  int s0 = blockIdx.x * 32, d0 = blockIdx.y * 32, bk = blockIdx.z;
  int b = bk >> 3, kvh = bk & 7;
  int tx = threadIdx.x & 31, ty = threadIdx.x >> 5;
  const U16* src = QKV + (long)(b * 2048) * 8192 + 6144 + kvh * 256;
#pragma unroll
  for (int r = 0; r < 4; ++r) {
    int s = s0 + ty + r * 8;
    tile[ty + r * 8][tx] = src[(long)s * 8192 + d0 + tx];
  }
  __syncthreads();
#pragma unroll
  for (int r = 0; r < 4; ++r) {
    int d = d0 + ty + r * 8;
    VT[((long)bk * 256 + d) * 2048 + s0 + tx] = tile[tx][ty + r * 8];
  }
}

// ---------------- RoPE tables (fp32) ----------------------------------------
__global__ __launch_bounds__(256) void k_rope_tables(float* __restrict__ cosT,
                                                     float* __restrict__ sinT) {
  int i = blockIdx.x * 256 + threadIdx.x;
  int s = i >> 7, d = i & 127;
  float freq = expf(-9.210340371976184f * (float)d / 128.0f);
  float ang = (float)s * freq;
  cosT[i] = cosf(ang);
  sinT[i] = sinf(ang);
}

// ---------------- RoPE in place on q,k sections of QKV ----------------------
__global__ __launch_bounds__(256) void k_rope(U16* __restrict__ qkv,
                                              const float* __restrict__ cosT,
                                              const float* __restrict__ sinT) {
  int i = blockIdx.x * 256 + threadIdx.x;
  int d = i & 127;
  int hh = (i >> 7) % 24;
  int row = i / 3072;
  int s = row & 2047;
  int col = (hh < 16) ? hh * 256 + d : 4096 + (hh - 16) * 256 + d;
  long base = (long)row * 8192 + col;
  float c = cosT[s * 128 + d], sn = sinT[s * 128 + d];
  float x1 = bf2f(qkv[base]), x2 = bf2f(qkv[base + 128]);
  qkv[base]       = f2bf(x1 * c - x2 * sn);
  qkv[base + 128] = f2bf(x2 * c + x1 * sn);
}

// ---------------- GEMM: C[M][N] = A[M][K] * Bt[N][K]^T ----------------------
// F32OUT=0: write bf16 (U16). F32OUT=1: write fp32.
// XCD-aware swizzle: requires gridDim.x*gridDim.y % 8 == 0 (both launches).
template <int F32OUT>
__global__ __launch_bounds__(256) void k_gemm(const U16* __restrict__ A,
                                              const U16* __restrict__ Bt,
                                              void* __restrict__ Cv,
                                              int M, int N, int K) {
  __shared__ __align__(16) U16 As[128 * 32];
  __shared__ __align__(16) U16 Bs[128 * 32];
  int nwg = gridDim.x * gridDim.y;
  int flat = blockIdx.y * gridDim.x + blockIdx.x;
  int cpx = nwg >> 3;
  int swz = (flat & 7) * cpx + (flat >> 3);
  int bx = swz % gridDim.x, by = swz / gridDim.x;
  int t = threadIdx.x, lane = t & 63, w = t >> 6;
  int m0 = by * 128, n0 = bx * 128;
  int wr = (w >> 1) * 64, wc = (w & 1) * 64;
  int l15 = lane & 15, l4 = lane >> 4;
  f32x4 acc[4][4] = {};
  int rowA = t >> 2, colg = (t & 3) * 8;
  const U16* gA0 = A + (long)(m0 + rowA) * K + colg;
  const U16* gA1 = A + (long)(m0 + 64 + rowA) * K + colg;
  const U16* gB0 = Bt + (long)(n0 + rowA) * K + colg;
  const U16* gB1 = Bt + (long)(n0 + 64 + rowA) * K + colg;
  char* lA0 = (char*)As + w * 1024;
  char* lA1 = (char*)As + 4096 + w * 1024;
  char* lB0 = (char*)Bs + w * 1024;
  char* lB1 = (char*)Bs + 4096 + w * 1024;

  for (int k0 = 0; k0 < K; k0 += 32) {
    gload_lds16(gA0 + k0, lA0);
    gload_lds16(gA1 + k0, lA1);
    gload_lds16(gB0 + k0, lB0);
    gload_lds16(gB1 + k0, lB1);
    asm volatile("s_waitcnt vmcnt(0)" ::: "memory");
    __syncthreads();
    bf16x8 af[4], bb[4];
#pragma unroll
    for (int m = 0; m < 4; ++m)
      af[m] = *(const bf16x8*)&As[(wr + m * 16 + l15) * 32 + l4 * 8];
#pragma unroll
    for (int n = 0; n < 4; ++n)
      bb[n] = *(const bf16x8*)&Bs[(wc + n * 16 + l15) * 32 + l4 * 8];
#pragma unroll
    for (int m = 0; m < 4; ++m)
#pragma unroll
      for (int n = 0; n < 4; ++n)
        acc[m][n] = __builtin_amdgcn_mfma_f32_16x16x32_bf16(af[m], bb[n], acc[m][n], 0, 0, 0);
    __syncthreads();
  }
#pragma unroll
  for (int m = 0; m < 4; ++m)
#pragma unroll
    for (int jj = 0; jj < 4; ++jj) {
      int row = m0 + wr + m * 16 + l4 * 4 + jj;
      if (F32OUT) {
        float* cp = (float*)Cv + (long)row * N + n0 + wc + l15;
#pragma unroll
        for (int n = 0; n < 4; ++n) cp[n * 16] = acc[m][n][jj];
      } else {
        U16* cp = (U16*)Cv + (long)row * N + n0 + wc + l15;
#pragma unroll
        for (int n = 0; n < 4; ++n) cp[n * 16] = f2bf(acc[m][n][jj]);
      }
    }
}

// ---------------- banded GQA attention (v3: barrier-free, direct-global) ----
// 4 waves/block, wave w owns q rows s0+w*16..+15. K fragments read directly
// from global QKV; V fragments from pre-transposed VT. No K/V LDS staging, no
// __syncthreads in the K-loop. Shuffle softmax + defer-max (THR=8).
__global__ __launch_bounds__(256) void k_attn(const U16* __restrict__ QKV,
                                              const U16* __restrict__ VT,
                                              U16* __restrict__ O) {
  __shared__ __align__(16) U16 Plds[4][16 * 40];
  int t = threadIdx.x, lane = t & 63, w = t >> 6;
  int qb = blockIdx.x, h = blockIdx.y, b = blockIdx.z;
  int s0 = qb * 64;
  int kvh = h >> 1;
  long rowOff = (long)b * 2048 * 8192;
  const U16* Qb = QKV + rowOff + h * 256;
  const U16* Kb = QKV + rowOff + 4096 + kvh * 256;
  const U16* VTb = VT + (long)(b * 8 + kvh) * 256 * 2048;

  int l15 = lane & 15, l4 = lane >> 4;

  bf16x8 qf[8];
  {
    const U16* qp = Qb + (long)(s0 + w * 16 + l15) * 8192 + l4 * 8;
#pragma unroll
    for (int kc = 0; kc < 8; ++kc) qf[kc] = *(const bf16x8*)(qp + kc * 32);
  }
  f32x4 acc[16] = {};
  float mrun = -1e30f, lrun = 0.0f;
  int qpos = s0 + w * 16 + l15;

  int kstart = s0 - 1024; if (kstart < 0) kstart = 0;
  int kend = s0 + 64 + 1024; if (kend > 2048) kend = 2048;

  const U16* kp0 = Kb + (long)(kstart + l15) * 8192 + l4 * 8;
  const U16* kp1 = kp0 + (long)16 * 8192;
  const U16* vp  = VTb + (long)l15 * 2048 + kstart + l4 * 8;

  for (int k0 = kstart; k0 < kend; k0 += 32) {
    // ---- QK^T: A = K-tile (direct global), B = Q^T; D[key][q] ----
    f32x4 sAcc[2] = {};
    __builtin_amdgcn_s_setprio(1);
#pragma unroll
    for (int kc = 0; kc < 8; ++kc) {
      bf16x8 a0 = *(const bf16x8*)(kp0 + kc * 32);
      bf16x8 a1 = *(const bf16x8*)(kp1 + kc * 32);
      sAcc[0] = __builtin_amdgcn_mfma_f32_16x16x32_bf16(a0, qf[kc], sAcc[0], 0, 0, 0);
      sAcc[1] = __builtin_amdgcn_mfma_f32_16x16x32_bf16(a1, qf[kc], sAcc[1], 0, 0, 0);
    }
    __builtin_amdgcn_s_setprio(0);
    // ---- softcap + band mask ----
    float sv[8];
#pragma unroll
    for (int mp = 0; mp < 2; ++mp)
#pragma unroll
      for (int jj = 0; jj < 4; ++jj) {
        int key = k0 + mp * 16 + l4 * 4 + jj;
        float x = sAcc[mp][jj] * 0.00125f;      // *1/sqrt(256) /50
        float ex = __expf(2.0f * x);
        float z = 50.0f * (ex - 1.0f) / (ex + 1.0f);
        int dd = qpos - key;
        if (dd < -1024 || dd > 1024) z = -3e38f;
        sv[mp * 4 + jj] = z;
      }
    // ---- shuffle softmax over the 4-lane q-group (l15, +16, +32, +48) ----
    float tmax = sv[0];
#pragma unroll
    for (int i = 1; i < 8; ++i) tmax = fmaxf(tmax, sv[i]);
    tmax = fmaxf(tmax, __shfl_xor(tmax, 16));
    tmax = fmaxf(tmax, __shfl_xor(tmax, 32));
    bool skipall = __all((tmax <= mrun + 8.0f) ? 1 : 0) != 0;
    float mnew = skipall ? mrun : fmaxf(mrun, tmax);
    float pex[8];
    float psum = 0.0f;
#pragma unroll
    for (int i = 0; i < 8; ++i) { pex[i] = __expf(sv[i] - mnew); psum += pex[i]; }
    psum += __shfl_xor(psum, 16);
    psum += __shfl_xor(psum, 32);
    if (skipall) {
      lrun += psum;
    } else {
      float esc = __expf(mrun - mnew);
      f32x4 ev;
#pragma unroll
      for (int jj = 0; jj < 4; ++jj) ev[jj] = __shfl(esc, l4 * 4 + jj);
#pragma unroll
      for (int n = 0; n < 16; ++n) acc[n] *= ev;
      lrun = lrun * esc + psum;
      mrun = mnew;
    }
    // ---- P -> per-wave Plds (packed u32), layout fix for A-fragment ----
#pragma unroll
    for (int mp = 0; mp < 2; ++mp)
#pragma unroll
      for (int j2 = 0; j2 < 2; ++j2) {
        unsigned lo = f2bf(pex[mp * 4 + j2 * 2]);
        unsigned hi = f2bf(pex[mp * 4 + j2 * 2 + 1]);
        *(unsigned*)&Plds[w][l15 * 40 + mp * 16 + l4 * 4 + j2 * 2] = lo | (hi << 16);
      }
    asm volatile("s_waitcnt lgkmcnt(0)" ::: "memory");
    __builtin_amdgcn_sched_barrier(0);
    bf16x8 pa = *(const bf16x8*)&Plds[w][l15 * 40 + l4 * 8];
    // ---- PV: A = P, B = V^T rows (direct global) ----
    __builtin_amdgcn_s_setprio(1);
#pragma unroll
    for (int n = 0; n < 16; ++n) {
      bf16x8 vb = *(const bf16x8*)(vp + (long)n * 16 * 2048);
      acc[n] = __builtin_amdgcn_mfma_f32_16x16x32_bf16(pa, vb, acc[n], 0, 0, 0);
    }
    __builtin_amdgcn_s_setprio(0);
    kp0 += (long)32 * 8192;
    kp1 += (long)32 * 8192;
    vp  += 32;
  }
  // ---- epilogue: normalize and store ----
  f32x4 linv;
#pragma unroll
  for (int jj = 0; jj < 4; ++jj) linv[jj] = 1.0f / __shfl(lrun, l4 * 4 + jj);
#pragma unroll
  for (int jj = 0; jj < 4; ++jj) {
    int row = s0 + w * 16 + l4 * 4 + jj;
    U16* op = O + ((long)b * 2048 + row) * 4096 + h * 256 + l15;
#pragma unroll
    for (int n = 0; n < 16; ++n) op[n * 16] = f2bf(acc[n][jj] * linv[jj]);
  }
}

// ----------------------------------------------------------------------------
extern "C" void kernel_launch(void* const* d_in, const int* in_sizes, int n_in,
                              void* d_out, int out_size, void* d_ws, size_t ws_size,
                              hipStream_t stream) {
  if (n_in < 5) return;
  const float* hid = (const float*)d_in[0];
  const float* Wq  = (const float*)d_in[1];
  const float* Wk  = (const float*)d_in[2];
  const float* Wv  = (const float*)d_in[3];
  const float* Wo  = (const float*)d_in[4];

  char* ws = (char*)d_ws;
  size_t off = 0;
  auto alloc = [&](size_t bytes) {
    char* p = ws + off;
    off += (bytes + 255) & ~(size_t)255;
    return p;
  };
  float* cosT = (float*)alloc((size_t)2048 * 128 * 4);
  float* sinT = (float*)alloc((size_t)2048 * 128 * 4);
  U16*   Xb   = (U16*)alloc((size_t)4096 * 3584 * 2);   // reused: VT, then Wot
  U16*   Wt   = (U16*)alloc((size_t)8192 * 3584 * 2);   // reused: AttO
  U16*   QKV  = (U16*)alloc((size_t)4096 * 8192 * 2);
  if (off > ws_size) return;
  U16* VT   = Xb;                 // 16 * 256 * 2048 * 2 B = 16.8 MB < |Xb|
  U16* Wot  = Xb;                 // written after attn (VT dead by then)
  U16* AttO = Wt;

  k_convert<<<7168, 256, 0, stream>>>(hid, Xb, (long)4096 * 3584);
  k_transpose<<<dim3(128, 112), 256, 0, stream>>>(Wq, Wt, 3584, 4096);
  k_transpose<<<dim3(64, 112), 256, 0, stream>>>(Wk, Wt + (size_t)4096 * 3584, 3584, 2048);
  k_transpose<<<dim3(64, 112), 256, 0, stream>>>(Wv, Wt + (size_t)6144 * 3584, 3584, 2048);
  k_rope_tables<<<1024, 256, 0, stream>>>(cosT, sinT);
  k_gemm<0><<<dim3(64, 32), 256, 0, stream>>>(Xb, Wt, QKV, 4096, 8192, 3584);
  k_vtrans<<<dim3(64, 8, 16), 256, 0, stream>>>(QKV, VT);
  k_rope<<<49152, 256, 0, stream>>>(QKV, cosT, sinT);
  k_attn<<<dim3(32, 16, 2), 256, 0, stream>>>(QKV, VT, AttO);
  k_transpose<<<dim3(112, 128), 256, 0, stream>>>(Wo, Wot, 4096, 3584);
  k_gemm<1><<<dim3(28, 32), 256, 0, stream>>>(AttO, Wot, d_out, 4096, 3584, 4096);
}

// Round 7
// 870.454 us; speedup vs baseline: 1.7468x; 1.7468x over previous
//
#include <hip/hip_runtime.h>
#include <stdint.h>

typedef unsigned short U16;
typedef float f32x4 __attribute__((ext_vector_type(4)));
typedef __bf16 bf16x8 __attribute__((ext_vector_type(8)));

static __device__ __forceinline__ U16 f2bf(float x) {
  union { float f; unsigned u; } v; v.f = x;
  unsigned r = v.u + 0x7FFFu + ((v.u >> 16) & 1u);
  return (U16)(r >> 16);
}
static __device__ __forceinline__ float bf2f(U16 h) {
  union { unsigned u; float f; } v; v.u = ((unsigned)h) << 16;
  return v.f;
}

static __device__ __forceinline__ void gload_lds16(const void* g, void* l) {
  __builtin_amdgcn_global_load_lds(
      (const __attribute__((address_space(1))) void*)g,
      (__attribute__((address_space(3))) void*)l, 16, 0, 0);
}

// ---------------- hidden (fp32) -> bf16 -------------------------------------
__global__ __launch_bounds__(256) void k_convert(const float* __restrict__ src,
                                                 U16* __restrict__ dst, long n) {
  long base = ((long)blockIdx.x * 256 + threadIdx.x) * 8;
  if (base >= n) return;
  const float4* s = (const float4*)(src + base);
  float4 a = s[0], b = s[1];
  U16 o[8] = { f2bf(a.x), f2bf(a.y), f2bf(a.z), f2bf(a.w),
               f2bf(b.x), f2bf(b.y), f2bf(b.z), f2bf(b.w) };
  *(uint4*)(dst + base) = *(const uint4*)o;
}

// ---------------- W[K][N] (fp32) -> Wt[N][K] bf16 ----------------------------
__global__ __launch_bounds__(256) void k_transpose(const float* __restrict__ src,
                                                   U16* __restrict__ dst,
                                                   int K, int N) {
  __shared__ U16 tile[32][33];
  int n0 = blockIdx.x * 32, k0 = blockIdx.y * 32;
  int tx = threadIdx.x & 31, ty = threadIdx.x >> 5;
#pragma unroll
  for (int r = 0; r < 4; ++r) {
    int k = k0 + ty + r * 8;
    tile[ty + r * 8][tx] = f2bf(src[(long)k * N + n0 + tx]);
  }
  __syncthreads();
#pragma unroll
  for (int r = 0; r < 4; ++r) {
    int n = n0 + ty + r * 8;
    dst[(long)n * K + k0 + tx] = tile[tx][ty + r * 8];
  }
}

// ---- V section of QKV -> VT tiled [bk][sTile=64][d=256][s32=32] bf16 -------
__global__ __launch_bounds__(256) void k_vtrans(const U16* __restrict__ QKV,
                                                U16* __restrict__ VT) {
  __shared__ U16 tile[32][33];
  int s0 = blockIdx.x * 32, d0 = blockIdx.y * 32, bk = blockIdx.z;
  int b = bk >> 3, kvh = bk & 7;
  int tx = threadIdx.x & 31, ty = threadIdx.x >> 5;
  const U16* src = QKV + (long)(b * 2048) * 8192 + 6144 + kvh * 256;
#pragma unroll
  for (int r = 0; r < 4; ++r) {
    int s = s0 + ty + r * 8;
    tile[ty + r * 8][tx] = src[(long)s * 8192 + d0 + tx];
  }
  __syncthreads();
  long tbase = ((long)bk * 64 + (s0 >> 5)) * 8192;   // 256*32 per tile
#pragma unroll
  for (int r = 0; r < 4; ++r) {
    int d = d0 + ty + r * 8;
    VT[tbase + d * 32 + tx] = tile[tx][ty + r * 8];
  }
}

// ---------------- RoPE tables (fp32) ----------------------------------------
__global__ __launch_bounds__(256) void k_rope_tables(float* __restrict__ cosT,
                                                     float* __restrict__ sinT) {
  int i = blockIdx.x * 256 + threadIdx.x;
  int s = i >> 7, d = i & 127;
  float freq = expf(-9.210340371976184f * (float)d / 128.0f);
  float ang = (float)s * freq;
  cosT[i] = cosf(ang);
  sinT[i] = sinf(ang);
}

// ---------------- RoPE in place on q,k sections of QKV ----------------------
__global__ __launch_bounds__(256) void k_rope(U16* __restrict__ qkv,
                                              const float* __restrict__ cosT,
                                              const float* __restrict__ sinT) {
  int i = blockIdx.x * 256 + threadIdx.x;
  int d = i & 127;
  int hh = (i >> 7) % 24;
  int row = i / 3072;
  int s = row & 2047;
  int col = (hh < 16) ? hh * 256 + d : 4096 + (hh - 16) * 256 + d;
  long base = (long)row * 8192 + col;
  float c = cosT[s * 128 + d], sn = sinT[s * 128 + d];
  float x1 = bf2f(qkv[base]), x2 = bf2f(qkv[base + 128]);
  qkv[base]       = f2bf(x1 * c - x2 * sn);
  qkv[base + 128] = f2bf(x2 * c + x1 * sn);
}

// ---------------- GEMM: C[M][N] = A[M][K] * Bt[N][K]^T ----------------------
template <int F32OUT>
__global__ __launch_bounds__(256) void k_gemm(const U16* __restrict__ A,
                                              const U16* __restrict__ Bt,
                                              void* __restrict__ Cv,
                                              int M, int N, int K) {
  __shared__ __align__(16) U16 As[128 * 32];
  __shared__ __align__(16) U16 Bs[128 * 32];
  int nwg = gridDim.x * gridDim.y;
  int flat = blockIdx.y * gridDim.x + blockIdx.x;
  int cpx = nwg >> 3;
  int swz = (flat & 7) * cpx + (flat >> 3);
  int bx = swz % gridDim.x, by = swz / gridDim.x;
  int t = threadIdx.x, lane = t & 63, w = t >> 6;
  int m0 = by * 128, n0 = bx * 128;
  int wr = (w >> 1) * 64, wc = (w & 1) * 64;
  int l15 = lane & 15, l4 = lane >> 4;
  f32x4 acc[4][4] = {};
  int rowA = t >> 2, colg = (t & 3) * 8;
  const U16* gA0 = A + (long)(m0 + rowA) * K + colg;
  const U16* gA1 = A + (long)(m0 + 64 + rowA) * K + colg;
  const U16* gB0 = Bt + (long)(n0 + rowA) * K + colg;
  const U16* gB1 = Bt + (long)(n0 + 64 + rowA) * K + colg;
  char* lA0 = (char*)As + w * 1024;
  char* lA1 = (char*)As + 4096 + w * 1024;
  char* lB0 = (char*)Bs + w * 1024;
  char* lB1 = (char*)Bs + 4096 + w * 1024;

  for (int k0 = 0; k0 < K; k0 += 32) {
    gload_lds16(gA0 + k0, lA0);
    gload_lds16(gA1 + k0, lA1);
    gload_lds16(gB0 + k0, lB0);
    gload_lds16(gB1 + k0, lB1);
    asm volatile("s_waitcnt vmcnt(0)" ::: "memory");
    __syncthreads();
    bf16x8 af[4], bb[4];
#pragma unroll
    for (int m = 0; m < 4; ++m)
      af[m] = *(const bf16x8*)&As[(wr + m * 16 + l15) * 32 + l4 * 8];
#pragma unroll
    for (int n = 0; n < 4; ++n)
      bb[n] = *(const bf16x8*)&Bs[(wc + n * 16 + l15) * 32 + l4 * 8];
#pragma unroll
    for (int m = 0; m < 4; ++m)
#pragma unroll
      for (int n = 0; n < 4; ++n)
        acc[m][n] = __builtin_amdgcn_mfma_f32_16x16x32_bf16(af[m], bb[n], acc[m][n], 0, 0, 0);
    __syncthreads();
  }
#pragma unroll
  for (int m = 0; m < 4; ++m)
#pragma unroll
    for (int jj = 0; jj < 4; ++jj) {
      int row = m0 + wr + m * 16 + l4 * 4 + jj;
      if (F32OUT) {
        float* cp = (float*)Cv + (long)row * N + n0 + wc + l15;
#pragma unroll
        for (int n = 0; n < 4; ++n) cp[n * 16] = acc[m][n][jj];
      } else {
        U16* cp = (U16*)Cv + (long)row * N + n0 + wc + l15;
#pragma unroll
        for (int n = 0; n < 4; ++n) cp[n * 16] = f2bf(acc[m][n][jj]);
      }
    }
}

// ---------------- banded GQA attention (v5: gload_lds dbuf + counted vmcnt) -
// 4 waves/block, wave w owns q rows s0+w*16..+15. K[32][256] and V[256][32]
// tiles staged async via global_load_lds (linear dest, source-swizzled);
// reads use the matching XOR so ds_read_b128 is ~2-way conflict (free).
// Double-buffered; vmcnt(8) counted waits; raw s_barrier (no drain in loop).
__global__ __launch_bounds__(256) void k_attn(const U16* __restrict__ QKV,
                                              const U16* __restrict__ VT,
                                              U16* __restrict__ O) {
  __shared__ __align__(16) U16 Ks[2][32 * 256];
  __shared__ __align__(16) U16 Vs[2][256 * 32];
  __shared__ __align__(16) U16 Plds[4][16 * 40];
  int t = threadIdx.x, lane = t & 63, w = t >> 6;
  // chunked XCD swizzle: consecutive logical blocks (same h, adjacent qb)
  // land on the same XCD -> K/V slice per XCD ~4MB = L2.
  int flat = blockIdx.x + 32 * (blockIdx.y + 16 * blockIdx.z);
  int l = (flat & 7) * 128 + (flat >> 3);
  int qb = l & 31, h = (l >> 5) & 15, b = l >> 9;
  int s0 = qb * 64;
  int kvh = h >> 1;
  long rowOff = (long)b * 2048 * 8192;
  const U16* Qb = QKV + rowOff + h * 256;
  const U16* Kb = QKV + rowOff + 4096 + kvh * 256;
  const U16* VTb = VT + (long)(b * 8 + kvh) * 64 * 8192;  // tiled [sT][d][32]

  int l15 = lane & 15, l4 = lane >> 4;

  bf16x8 qf[8];
  {
    const U16* qp = Qb + (long)(s0 + w * 16 + l15) * 8192 + l4 * 8;
#pragma unroll
    for (int kc = 0; kc < 8; ++kc) qf[kc] = *(const bf16x8*)(qp + kc * 32);
  }
  // force Q loads to complete so vmcnt counting below is exact
  asm volatile("s_waitcnt vmcnt(0)" ::: "memory");

  f32x4 acc[16] = {};
  float mrun = -1e30f, lrun = 0.0f;
  int qpos = s0 + w * 16 + l15;

  int kstart = s0 - 1024; if (kstart < 0) kstart = 0;
  int kend = s0 + 64 + 1024; if (kend > 2048) kend = 2048;

  // stage tile k0 into buffer buf: 4 K-issues + 4 V-issues per thread-set
  auto stage = [&](int buf, int k0) {
#pragma unroll
    for (int i = 0; i < 4; ++i) {
      int g = i * 256 + t;                 // 16B granule id, 0..1023
      int row = g >> 5, c = g & 31;
      int cs = c ^ (row & 7);              // K source swizzle (involution)
      gload_lds16(Kb + (long)(k0 + row) * 8192 + cs * 8,
                  (char*)&Ks[buf][0] + i * 4096 + w * 1024);
    }
    const U16* vtile = VTb + (long)(k0 >> 5) * 8192;
#pragma unroll
    for (int i = 0; i < 4; ++i) {
      int g = i * 256 + t;
      int d = g >> 2, c = g & 3;
      int cs = c ^ ((d >> 1) & 3);         // V source swizzle (involution)
      gload_lds16(vtile + d * 32 + cs * 8,
                  (char*)&Vs[buf][0] + i * 4096 + w * 1024);
    }
  };

  auto compute = [&](int buf, int k0) {
    // ---- QK^T: A = K rows (swizzled read), B = Q^T; D[key][q] ----
    f32x4 sAcc[2] = {};
    __builtin_amdgcn_s_setprio(1);
#pragma unroll
    for (int kc = 0; kc < 8; ++kc) {
      int c0 = ((kc * 4 + l4) ^ (l15 & 7)) * 8;
      bf16x8 a0 = *(const bf16x8*)&Ks[buf][l15 * 256 + c0];
      bf16x8 a1 = *(const bf16x8*)&Ks[buf][(16 + l15) * 256 + c0];
      sAcc[0] = __builtin_amdgcn_mfma_f32_16x16x32_bf16(a0, qf[kc], sAcc[0], 0, 0, 0);
      sAcc[1] = __builtin_amdgcn_mfma_f32_16x16x32_bf16(a1, qf[kc], sAcc[1], 0, 0, 0);
    }
    __builtin_amdgcn_s_setprio(0);
    // ---- softcap + band mask ----
    float sv[8];
#pragma unroll
    for (int mp = 0; mp < 2; ++mp)
#pragma unroll
      for (int jj = 0; jj < 4; ++jj) {
        int key = k0 + mp * 16 + l4 * 4 + jj;
        float x = sAcc[mp][jj] * 0.00125f;      // *1/sqrt(256) /50
        float ex = __expf(2.0f * x);
        float z = 50.0f * (ex - 1.0f) / (ex + 1.0f);
        int dd = qpos - key;
        if (dd < -1024 || dd > 1024) z = -3e38f;
        sv[mp * 4 + jj] = z;
      }
    // ---- shuffle softmax + defer-max (THR=8) ----
    float tmax = sv[0];
#pragma unroll
    for (int i = 1; i < 8; ++i) tmax = fmaxf(tmax, sv[i]);
    tmax = fmaxf(tmax, __shfl_xor(tmax, 16));
    tmax = fmaxf(tmax, __shfl_xor(tmax, 32));
    bool skipall = __all((tmax <= mrun + 8.0f) ? 1 : 0) != 0;
    float mnew = skipall ? mrun : fmaxf(mrun, tmax);
    float pex[8];
    float psum = 0.0f;
#pragma unroll
    for (int i = 0; i < 8; ++i) { pex[i] = __expf(sv[i] - mnew); psum += pex[i]; }
    psum += __shfl_xor(psum, 16);
    psum += __shfl_xor(psum, 32);
    if (skipall) {
      lrun += psum;
    } else {
      float esc = __expf(mrun - mnew);
      f32x4 ev;
#pragma unroll
      for (int jj = 0; jj < 4; ++jj) ev[jj] = __shfl(esc, l4 * 4 + jj);
#pragma unroll
      for (int n = 0; n < 16; ++n) acc[n] *= ev;
      lrun = lrun * esc + psum;
      mrun = mnew;
    }
    // ---- P -> per-wave Plds (packed u32) ----
#pragma unroll
    for (int mp = 0; mp < 2; ++mp)
#pragma unroll
      for (int j2 = 0; j2 < 2; ++j2) {
        unsigned lo = f2bf(pex[mp * 4 + j2 * 2]);
        unsigned hi = f2bf(pex[mp * 4 + j2 * 2 + 1]);
        *(unsigned*)&Plds[w][l15 * 40 + mp * 16 + l4 * 4 + j2 * 2] = lo | (hi << 16);
      }
    asm volatile("s_waitcnt lgkmcnt(0)" ::: "memory");
    __builtin_amdgcn_sched_barrier(0);
    bf16x8 pa = *(const bf16x8*)&Plds[w][l15 * 40 + l4 * 8];
    // ---- PV: A = P, B = V^T rows (swizzled read) ----
    __builtin_amdgcn_s_setprio(1);
#pragma unroll
    for (int n = 0; n < 16; ++n) {
      int d = n * 16 + l15;
      int c = (l4 ^ ((d >> 1) & 3)) * 8;
      bf16x8 vb = *(const bf16x8*)&Vs[buf][d * 32 + c];
      acc[n] = __builtin_amdgcn_mfma_f32_16x16x32_bf16(pa, vb, acc[n], 0, 0, 0);
    }
    __builtin_amdgcn_s_setprio(0);
  };

  int cur = 0;
  stage(0, kstart);
  for (int k0 = kstart; k0 < kend - 32; k0 += 32) {
    stage(cur ^ 1, k0 + 32);
    asm volatile("s_waitcnt vmcnt(8)" ::: "memory");   // tile k0's 8 done
    __builtin_amdgcn_s_barrier();
    __builtin_amdgcn_sched_barrier(0);
    compute(cur, k0);
    __builtin_amdgcn_s_barrier();                      // all waves done w/ cur
    cur ^= 1;
  }
  asm volatile("s_waitcnt vmcnt(0)" ::: "memory");
  __builtin_amdgcn_s_barrier();
  __builtin_amdgcn_sched_barrier(0);
  compute(cur, kend - 32);

  // ---- epilogue: normalize and store ----
  f32x4 linv;
#pragma unroll
  for (int jj = 0; jj < 4; ++jj) linv[jj] = 1.0f / __shfl(lrun, l4 * 4 + jj);
#pragma unroll
  for (int jj = 0; jj < 4; ++jj) {
    int row = s0 + w * 16 + l4 * 4 + jj;
    U16* op = O + ((long)b * 2048 + row) * 4096 + h * 256 + l15;
#pragma unroll
    for (int n = 0; n < 16; ++n) op[n * 16] = f2bf(acc[n][jj] * linv[jj]);
  }
}

// ----------------------------------------------------------------------------
extern "C" void kernel_launch(void* const* d_in, const int* in_sizes, int n_in,
                              void* d_out, int out_size, void* d_ws, size_t ws_size,
                              hipStream_t stream) {
  if (n_in < 5) return;
  const float* hid = (const float*)d_in[0];
  const float* Wq  = (const float*)d_in[1];
  const float* Wk  = (const float*)d_in[2];
  const float* Wv  = (const float*)d_in[3];
  const float* Wo  = (const float*)d_in[4];

  char* ws = (char*)d_ws;
  size_t off = 0;
  auto alloc = [&](size_t bytes) {
    char* p = ws + off;
    off += (bytes + 255) & ~(size_t)255;
    return p;
  };
  float* cosT = (float*)alloc((size_t)2048 * 128 * 4);
  float* sinT = (float*)alloc((size_t)2048 * 128 * 4);
  U16*   Xb   = (U16*)alloc((size_t)4096 * 3584 * 2);   // reused: VT, then Wot
  U16*   Wt   = (U16*)alloc((size_t)8192 * 3584 * 2);   // reused: AttO
  U16*   QKV  = (U16*)alloc((size_t)4096 * 8192 * 2);
  if (off > ws_size) return;
  U16* VT   = Xb;                 // 16*64*8192*2 B = 16.8 MB < |Xb|
  U16* Wot  = Xb;                 // written after attn (VT dead by then)
  U16* AttO = Wt;

  k_convert<<<7168, 256, 0, stream>>>(hid, Xb, (long)4096 * 3584);
  k_transpose<<<dim3(128, 112), 256, 0, stream>>>(Wq, Wt, 3584, 4096);
  k_transpose<<<dim3(64, 112), 256, 0, stream>>>(Wk, Wt + (size_t)4096 * 3584, 3584, 2048);
  k_transpose<<<dim3(64, 112), 256, 0, stream>>>(Wv, Wt + (size_t)6144 * 3584, 3584, 2048);
  k_rope_tables<<<1024, 256, 0, stream>>>(cosT, sinT);
  k_gemm<0><<<dim3(64, 32), 256, 0, stream>>>(Xb, Wt, QKV, 4096, 8192, 3584);
  k_vtrans<<<dim3(64, 8, 16), 256, 0, stream>>>(QKV, VT);
  k_rope<<<49152, 256, 0, stream>>>(QKV, cosT, sinT);
  k_attn<<<dim3(32, 16, 2), 256, 0, stream>>>(QKV, VT, AttO);
  k_transpose<<<dim3(112, 128), 256, 0, stream>>>(Wo, Wot, 4096, 3584);
  k_gemm<1><<<dim3(28, 32), 256, 0, stream>>>(AttO, Wot, d_out, 4096, 3584, 4096);
}

// Round 8
// 774.421 us; speedup vs baseline: 1.9634x; 1.1240x over previous
//
#include <hip/hip_runtime.h>
#include <stdint.h>

typedef unsigned short U16;
typedef float f32x4 __attribute__((ext_vector_type(4)));
typedef __bf16 bf16x8 __attribute__((ext_vector_type(8)));

static __device__ __forceinline__ U16 f2bf(float x) {
  union { float f; unsigned u; } v; v.f = x;
  unsigned r = v.u + 0x7FFFu + ((v.u >> 16) & 1u);
  return (U16)(r >> 16);
}
static __device__ __forceinline__ float bf2f(U16 h) {
  union { unsigned u; float f; } v; v.u = ((unsigned)h) << 16;
  return v.f;
}

static __device__ __forceinline__ void gload_lds16(const void* g, void* l) {
  __builtin_amdgcn_global_load_lds(
      (const __attribute__((address_space(1))) void*)g,
      (__attribute__((address_space(3))) void*)l, 16, 0, 0);
}

// ---------------- hidden (fp32) -> bf16 -------------------------------------
__global__ __launch_bounds__(256) void k_convert(const float* __restrict__ src,
                                                 U16* __restrict__ dst, long n) {
  long base = ((long)blockIdx.x * 256 + threadIdx.x) * 8;
  if (base >= n) return;
  const float4* s = (const float4*)(src + base);
  float4 a = s[0], b = s[1];
  U16 o[8] = { f2bf(a.x), f2bf(a.y), f2bf(a.z), f2bf(a.w),
               f2bf(b.x), f2bf(b.y), f2bf(b.z), f2bf(b.w) };
  *(uint4*)(dst + base) = *(const uint4*)o;
}

// ---------------- W[K][N] (fp32) -> Wt[N][K] bf16 ----------------------------
__global__ __launch_bounds__(256) void k_transpose(const float* __restrict__ src,
                                                   U16* __restrict__ dst,
                                                   int K, int N) {
  __shared__ U16 tile[32][33];
  int n0 = blockIdx.x * 32, k0 = blockIdx.y * 32;
  int tx = threadIdx.x & 31, ty = threadIdx.x >> 5;
#pragma unroll
  for (int r = 0; r < 4; ++r) {
    int k = k0 + ty + r * 8;
    tile[ty + r * 8][tx] = f2bf(src[(long)k * N + n0 + tx]);
  }
  __syncthreads();
#pragma unroll
  for (int r = 0; r < 4; ++r) {
    int n = n0 + ty + r * 8;
    dst[(long)n * K + k0 + tx] = tile[tx][ty + r * 8];
  }
}

// ---- V section of QKV -> VT tiled [bk][sTile=64][d=256][s32=32] bf16 -------
__global__ __launch_bounds__(256) void k_vtrans(const U16* __restrict__ QKV,
                                                U16* __restrict__ VT) {
  __shared__ U16 tile[32][33];
  int s0 = blockIdx.x * 32, d0 = blockIdx.y * 32, bk = blockIdx.z;
  int b = bk >> 3, kvh = bk & 7;
  int tx = threadIdx.x & 31, ty = threadIdx.x >> 5;
  const U16* src = QKV + (long)(b * 2048) * 8192 + 6144 + kvh * 256;
#pragma unroll
  for (int r = 0; r < 4; ++r) {
    int s = s0 + ty + r * 8;
    tile[ty + r * 8][tx] = src[(long)s * 8192 + d0 + tx];
  }
  __syncthreads();
  long tbase = ((long)bk * 64 + (s0 >> 5)) * 8192;   // 256*32 per tile
#pragma unroll
  for (int r = 0; r < 4; ++r) {
    int d = d0 + ty + r * 8;
    VT[tbase + d * 32 + tx] = tile[tx][ty + r * 8];
  }
}

// ---------------- RoPE tables (fp32) ----------------------------------------
__global__ __launch_bounds__(256) void k_rope_tables(float* __restrict__ cosT,
                                                     float* __restrict__ sinT) {
  int i = blockIdx.x * 256 + threadIdx.x;
  int s = i >> 7, d = i & 127;
  float freq = expf(-9.210340371976184f * (float)d / 128.0f);
  float ang = (float)s * freq;
  cosT[i] = cosf(ang);
  sinT[i] = sinf(ang);
}

// ---------------- RoPE in place on q,k sections of QKV ----------------------
__global__ __launch_bounds__(256) void k_rope(U16* __restrict__ qkv,
                                              const float* __restrict__ cosT,
                                              const float* __restrict__ sinT) {
  int i = blockIdx.x * 256 + threadIdx.x;
  int d = i & 127;
  int hh = (i >> 7) % 24;
  int row = i / 3072;
  int s = row & 2047;
  int col = (hh < 16) ? hh * 256 + d : 4096 + (hh - 16) * 256 + d;
  long base = (long)row * 8192 + col;
  float c = cosT[s * 128 + d], sn = sinT[s * 128 + d];
  float x1 = bf2f(qkv[base]), x2 = bf2f(qkv[base + 128]);
  qkv[base]       = f2bf(x1 * c - x2 * sn);
  qkv[base + 128] = f2bf(x2 * c + x1 * sn);
}

// ---------------- GEMM v2: 256x256 tile, 8 waves, 3-deep counted pipeline ---
// C[M][N] = A[M][K] * Bt[N][K]^T. BK=32, triple-buffered LDS (96 KB).
// Per iter: stage(t+2) -> compute(t) -> vmcnt(4) -> s_barrier.
// Invariant at iter t entry: tile t resident chip-wide, tile t+1's 4 loads
// outstanding. LDS swizzle c2 ^= (r&3)<<4 applied on BOTH gload source and
// ds_read (involution) -> frag reads hit the b128 bandwidth floor.
template <int F32OUT>
__global__ __launch_bounds__(512, 2) void k_gemm2(const U16* __restrict__ A,
                                                  const U16* __restrict__ Bt,
                                                  void* __restrict__ Cv,
                                                  int M, int N, int K) {
  __shared__ __align__(16) U16 Ab[3][256 * 32];
  __shared__ __align__(16) U16 Bb[3][256 * 32];
  int nwg = gridDim.x * gridDim.y;
  int flat = blockIdx.y * gridDim.x + blockIdx.x;
  int cpx = nwg >> 3;
  int swz = (flat & 7) * cpx + (flat >> 3);
  int bx = swz % gridDim.x, by = swz / gridDim.x;
  int t = threadIdx.x, lane = t & 63, w = t >> 6;
  int m0 = by * 256, n0 = bx * 256;
  int wm = w >> 2, wn = w & 3;
  int l15 = lane & 15, l4 = lane >> 4;

  f32x4 acc[8][4] = {};

  // staging addresses: issue i covers dest bytes (i*512+t)*16 of a 16 KB tile
  int r0 = t >> 2;                       // dest row for i=0 (0..127)
  int c20 = (t & 3) * 16;                // dest col-byte
  int cs0 = c20 ^ ((r0 & 3) << 4);       // swizzled source col (involution)
  const U16* gA0 = A + (long)(m0 + r0) * K + (cs0 >> 1);
  const U16* gA1 = A + (long)(m0 + 128 + r0) * K + (cs0 >> 1);   // (r+128)&3 == r&3
  const U16* gB0 = Bt + (long)(n0 + r0) * K + (cs0 >> 1);
  const U16* gB1 = Bt + (long)(n0 + 128 + r0) * K + (cs0 >> 1);

  auto stage = [&](int buf, int kt) {
    long k0 = (long)kt * 32;
    gload_lds16(gA0 + k0, (char*)&Ab[buf][0] + w * 1024);
    gload_lds16(gA1 + k0, (char*)&Ab[buf][0] + 8192 + w * 1024);
    gload_lds16(gB0 + k0, (char*)&Bb[buf][0] + w * 1024);
    gload_lds16(gB1 + k0, (char*)&Bb[buf][0] + 8192 + w * 1024);
  };

  auto compute = [&](int buf) {
    const char* Ac = (const char*)&Ab[buf][0];
    const char* Bc = (const char*)&Bb[buf][0];
    bf16x8 af[8], bb[4];
    int csw = (l4 * 16) ^ ((l15 & 3) << 4);   // r&3 == l15&3 for all frags
#pragma unroll
    for (int m = 0; m < 8; ++m) {
      int r = wm * 128 + m * 16 + l15;
      af[m] = *(const bf16x8*)(Ac + r * 64 + csw);
    }
#pragma unroll
    for (int n = 0; n < 4; ++n) {
      int r = wn * 64 + n * 16 + l15;
      bb[n] = *(const bf16x8*)(Bc + r * 64 + csw);
    }
    __builtin_amdgcn_s_setprio(1);
#pragma unroll
    for (int m = 0; m < 8; ++m)
#pragma unroll
      for (int n = 0; n < 4; ++n)
        acc[m][n] = __builtin_amdgcn_mfma_f32_16x16x32_bf16(af[m], bb[n], acc[m][n], 0, 0, 0);
    __builtin_amdgcn_s_setprio(0);
  };

  int T = K >> 5;
  stage(0, 0);
  stage(1, 1);
  asm volatile("s_waitcnt vmcnt(4)" ::: "memory");
  __builtin_amdgcn_sched_barrier(0);
  __builtin_amdgcn_s_barrier();
  __builtin_amdgcn_sched_barrier(0);

  int cur = 0, stb = 2;
  for (int kt = 0; kt < T - 2; ++kt) {
    stage(stb, kt + 2);
    compute(cur);
    asm volatile("s_waitcnt vmcnt(4)" ::: "memory");
    __builtin_amdgcn_sched_barrier(0);
    __builtin_amdgcn_s_barrier();
    __builtin_amdgcn_sched_barrier(0);
    cur = (cur + 1 == 3) ? 0 : cur + 1;
    stb = (stb + 1 == 3) ? 0 : stb + 1;
  }
  compute(cur);                                  // tile T-2
  asm volatile("s_waitcnt vmcnt(0)" ::: "memory");
  __builtin_amdgcn_sched_barrier(0);
  __builtin_amdgcn_s_barrier();
  __builtin_amdgcn_sched_barrier(0);
  cur = (cur + 1 == 3) ? 0 : cur + 1;
  compute(cur);                                  // tile T-1

  // epilogue
#pragma unroll
  for (int m = 0; m < 8; ++m)
#pragma unroll
    for (int jj = 0; jj < 4; ++jj) {
      int row = m0 + wm * 128 + m * 16 + l4 * 4 + jj;
      if (F32OUT) {
        float* cp = (float*)Cv + (long)row * N + n0 + wn * 64 + l15;
#pragma unroll
        for (int n = 0; n < 4; ++n) cp[n * 16] = acc[m][n][jj];
      } else {
        U16* cp = (U16*)Cv + (long)row * N + n0 + wn * 64 + l15;
#pragma unroll
        for (int n = 0; n < 4; ++n) cp[n * 16] = f2bf(acc[m][n][jj]);
      }
    }
}

// ---------------- banded GQA attention (v5, unchanged from round 7) ---------
__global__ __launch_bounds__(256) void k_attn(const U16* __restrict__ QKV,
                                              const U16* __restrict__ VT,
                                              U16* __restrict__ O) {
  __shared__ __align__(16) U16 Ks[2][32 * 256];
  __shared__ __align__(16) U16 Vs[2][256 * 32];
  __shared__ __align__(16) U16 Plds[4][16 * 40];
  int t = threadIdx.x, lane = t & 63, w = t >> 6;
  int flat = blockIdx.x + 32 * (blockIdx.y + 16 * blockIdx.z);
  int l = (flat & 7) * 128 + (flat >> 3);
  int qb = l & 31, h = (l >> 5) & 15, b = l >> 9;
  int s0 = qb * 64;
  int kvh = h >> 1;
  long rowOff = (long)b * 2048 * 8192;
  const U16* Qb = QKV + rowOff + h * 256;
  const U16* Kb = QKV + rowOff + 4096 + kvh * 256;
  const U16* VTb = VT + (long)(b * 8 + kvh) * 64 * 8192;

  int l15 = lane & 15, l4 = lane >> 4;

  bf16x8 qf[8];
  {
    const U16* qp = Qb + (long)(s0 + w * 16 + l15) * 8192 + l4 * 8;
#pragma unroll
    for (int kc = 0; kc < 8; ++kc) qf[kc] = *(const bf16x8*)(qp + kc * 32);
  }
  asm volatile("s_waitcnt vmcnt(0)" ::: "memory");

  f32x4 acc[16] = {};
  float mrun = -1e30f, lrun = 0.0f;
  int qpos = s0 + w * 16 + l15;

  int kstart = s0 - 1024; if (kstart < 0) kstart = 0;
  int kend = s0 + 64 + 1024; if (kend > 2048) kend = 2048;

  auto stage = [&](int buf, int k0) {
#pragma unroll
    for (int i = 0; i < 4; ++i) {
      int g = i * 256 + t;
      int row = g >> 5, c = g & 31;
      int cs = c ^ (row & 7);
      gload_lds16(Kb + (long)(k0 + row) * 8192 + cs * 8,
                  (char*)&Ks[buf][0] + i * 4096 + w * 1024);
    }
    const U16* vtile = VTb + (long)(k0 >> 5) * 8192;
#pragma unroll
    for (int i = 0; i < 4; ++i) {
      int g = i * 256 + t;
      int d = g >> 2, c = g & 3;
      int cs = c ^ ((d >> 1) & 3);
      gload_lds16(vtile + d * 32 + cs * 8,
                  (char*)&Vs[buf][0] + i * 4096 + w * 1024);
    }
  };

  auto compute = [&](int buf, int k0) {
    f32x4 sAcc[2] = {};
    __builtin_amdgcn_s_setprio(1);
#pragma unroll
    for (int kc = 0; kc < 8; ++kc) {
      int c0 = ((kc * 4 + l4) ^ (l15 & 7)) * 8;
      bf16x8 a0 = *(const bf16x8*)&Ks[buf][l15 * 256 + c0];
      bf16x8 a1 = *(const bf16x8*)&Ks[buf][(16 + l15) * 256 + c0];
      sAcc[0] = __builtin_amdgcn_mfma_f32_16x16x32_bf16(a0, qf[kc], sAcc[0], 0, 0, 0);
      sAcc[1] = __builtin_amdgcn_mfma_f32_16x16x32_bf16(a1, qf[kc], sAcc[1], 0, 0, 0);
    }
    __builtin_amdgcn_s_setprio(0);
    float sv[8];
#pragma unroll
    for (int mp = 0; mp < 2; ++mp)
#pragma unroll
      for (int jj = 0; jj < 4; ++jj) {
        int key = k0 + mp * 16 + l4 * 4 + jj;
        float x = sAcc[mp][jj] * 0.00125f;
        float ex = __expf(2.0f * x);
        float z = 50.0f * (ex - 1.0f) / (ex + 1.0f);
        int dd = qpos - key;
        if (dd < -1024 || dd > 1024) z = -3e38f;
        sv[mp * 4 + jj] = z;
      }
    float tmax = sv[0];
#pragma unroll
    for (int i = 1; i < 8; ++i) tmax = fmaxf(tmax, sv[i]);
    tmax = fmaxf(tmax, __shfl_xor(tmax, 16));
    tmax = fmaxf(tmax, __shfl_xor(tmax, 32));
    bool skipall = __all((tmax <= mrun + 8.0f) ? 1 : 0) != 0;
    float mnew = skipall ? mrun : fmaxf(mrun, tmax);
    float pex[8];
    float psum = 0.0f;
#pragma unroll
    for (int i = 0; i < 8; ++i) { pex[i] = __expf(sv[i] - mnew); psum += pex[i]; }
    psum += __shfl_xor(psum, 16);
    psum += __shfl_xor(psum, 32);
    if (skipall) {
      lrun += psum;
    } else {
      float esc = __expf(mrun - mnew);
      f32x4 ev;
#pragma unroll
      for (int jj = 0; jj < 4; ++jj) ev[jj] = __shfl(esc, l4 * 4 + jj);
#pragma unroll
      for (int n = 0; n < 16; ++n) acc[n] *= ev;
      lrun = lrun * esc + psum;
      mrun = mnew;
    }
#pragma unroll
    for (int mp = 0; mp < 2; ++mp)
#pragma unroll
      for (int j2 = 0; j2 < 2; ++j2) {
        unsigned lo = f2bf(pex[mp * 4 + j2 * 2]);
        unsigned hi = f2bf(pex[mp * 4 + j2 * 2 + 1]);
        *(unsigned*)&Plds[w][l15 * 40 + mp * 16 + l4 * 4 + j2 * 2] = lo | (hi << 16);
      }
    asm volatile("s_waitcnt lgkmcnt(0)" ::: "memory");
    __builtin_amdgcn_sched_barrier(0);
    bf16x8 pa = *(const bf16x8*)&Plds[w][l15 * 40 + l4 * 8];
    __builtin_amdgcn_s_setprio(1);
#pragma unroll
    for (int n = 0; n < 16; ++n) {
      int d = n * 16 + l15;
      int c = (l4 ^ ((d >> 1) & 3)) * 8;
      bf16x8 vb = *(const bf16x8*)&Vs[buf][d * 32 + c];
      acc[n] = __builtin_amdgcn_mfma_f32_16x16x32_bf16(pa, vb, acc[n], 0, 0, 0);
    }
    __builtin_amdgcn_s_setprio(0);
  };

  int cur = 0;
  stage(0, kstart);
  for (int k0 = kstart; k0 < kend - 32; k0 += 32) {
    stage(cur ^ 1, k0 + 32);
    asm volatile("s_waitcnt vmcnt(8)" ::: "memory");
    __builtin_amdgcn_s_barrier();
    __builtin_amdgcn_sched_barrier(0);
    compute(cur, k0);
    __builtin_amdgcn_s_barrier();
    cur ^= 1;
  }
  asm volatile("s_waitcnt vmcnt(0)" ::: "memory");
  __builtin_amdgcn_s_barrier();
  __builtin_amdgcn_sched_barrier(0);
  compute(cur, kend - 32);

  f32x4 linv;
#pragma unroll
  for (int jj = 0; jj < 4; ++jj) linv[jj] = 1.0f / __shfl(lrun, l4 * 4 + jj);
#pragma unroll
  for (int jj = 0; jj < 4; ++jj) {
    int row = s0 + w * 16 + l4 * 4 + jj;
    U16* op = O + ((long)b * 2048 + row) * 4096 + h * 256 + l15;
#pragma unroll
    for (int n = 0; n < 16; ++n) op[n * 16] = f2bf(acc[n][jj] * linv[jj]);
  }
}

// ----------------------------------------------------------------------------
extern "C" void kernel_launch(void* const* d_in, const int* in_sizes, int n_in,
                              void* d_out, int out_size, void* d_ws, size_t ws_size,
                              hipStream_t stream) {
  if (n_in < 5) return;
  const float* hid = (const float*)d_in[0];
  const float* Wq  = (const float*)d_in[1];
  const float* Wk  = (const float*)d_in[2];
  const float* Wv  = (const float*)d_in[3];
  const float* Wo  = (const float*)d_in[4];

  char* ws = (char*)d_ws;
  size_t off = 0;
  auto alloc = [&](size_t bytes) {
    char* p = ws + off;
    off += (bytes + 255) & ~(size_t)255;
    return p;
  };
  float* cosT = (float*)alloc((size_t)2048 * 128 * 4);
  float* sinT = (float*)alloc((size_t)2048 * 128 * 4);
  U16*   Xb   = (U16*)alloc((size_t)4096 * 3584 * 2);   // reused: VT, then Wot
  U16*   Wt   = (U16*)alloc((size_t)8192 * 3584 * 2);   // reused: AttO
  U16*   QKV  = (U16*)alloc((size_t)4096 * 8192 * 2);
  if (off > ws_size) return;
  U16* VT   = Xb;                 // 16*64*8192*2 B = 16.8 MB < |Xb|
  U16* Wot  = Xb;                 // written after attn (VT dead by then)
  U16* AttO = Wt;

  k_convert<<<7168, 256, 0, stream>>>(hid, Xb, (long)4096 * 3584);
  k_transpose<<<dim3(128, 112), 256, 0, stream>>>(Wq, Wt, 3584, 4096);
  k_transpose<<<dim3(64, 112), 256, 0, stream>>>(Wk, Wt + (size_t)4096 * 3584, 3584, 2048);
  k_transpose<<<dim3(64, 112), 256, 0, stream>>>(Wv, Wt + (size_t)6144 * 3584, 3584, 2048);
  k_rope_tables<<<1024, 256, 0, stream>>>(cosT, sinT);
  k_gemm2<0><<<dim3(32, 16), 512, 0, stream>>>(Xb, Wt, QKV, 4096, 8192, 3584);
  k_vtrans<<<dim3(64, 8, 16), 256, 0, stream>>>(QKV, VT);
  k_rope<<<49152, 256, 0, stream>>>(QKV, cosT, sinT);
  k_attn<<<dim3(32, 16, 2), 256, 0, stream>>>(QKV, VT, AttO);
  k_transpose<<<dim3(112, 128), 256, 0, stream>>>(Wo, Wot, 4096, 3584);
  k_gemm2<1><<<dim3(14, 16), 512, 0, stream>>>(AttO, Wot, d_out, 4096, 3584, 4096);
}